// Round 1
// baseline (953.097 us; speedup 1.0000x reference)
//
#include <hip/hip_runtime.h>

#define THREADS 256

// ---------------- zero workspace (Tx + deg) ----------------
__global__ void zero_kernel(float* __restrict__ p, long n) {
  long i = (long)blockIdx.x * blockDim.x + threadIdx.x;
  long stride = (long)gridDim.x * blockDim.x;
  for (; i < n; i += stride) p[i] = 0.0f;
}

// ---------------- deg[row[e]] += w[e] ----------------
__global__ void deg_kernel(const float* __restrict__ w, const int* __restrict__ row,
                           float* __restrict__ deg, int E) {
  int e = blockIdx.x * blockDim.x + threadIdx.x;
  if (e < E) atomicAdd(&deg[row[e]], w[e]);
}

// ---------------- disq = deg>0 ? rsqrt(deg) : 0 (in place) ----------------
__global__ void disq_kernel(float* __restrict__ deg, int n) {
  int i = blockIdx.x * blockDim.x + threadIdx.x;
  if (i < n) {
    float d = deg[i];
    deg[i] = (d > 0.0f) ? rsqrtf(d) : 0.0f;
  }
}

// ---------------- norm_e = -w_e * disq[row] * disq[col] ----------------
__global__ void norm_kernel(const float* __restrict__ w, const int* __restrict__ row,
                            const int* __restrict__ col, const float* __restrict__ disq,
                            float* __restrict__ nrm, int E) {
  int e = blockIdx.x * blockDim.x + threadIdx.x;
  if (e < E) nrm[e] = -w[e] * disq[row[e]] * disq[col[e]];
}

// ---------------- Tx[col] += norm * x[row], 8 threads per edge ----------------
__global__ void scatter_kernel(const float* __restrict__ x, const float* __restrict__ nrm,
                               const int* __restrict__ row, const int* __restrict__ col,
                               float* __restrict__ Tx, long E8) {
  long t = (long)blockIdx.x * blockDim.x + threadIdx.x;
  if (t >= E8) return;
  long e = t >> 3;
  int j = (int)(t & 7);
  int r = row[e];
  int c = col[e];
  float nm = nrm[e];
  float4 xv = *(const float4*)(x + (long)r * 32 + j * 4);
  float* dst = Tx + (long)c * 32 + j * 4;
  atomicAdd(dst + 0, nm * xv.x);
  atomicAdd(dst + 1, nm * xv.y);
  atomicAdd(dst + 2, nm * xv.z);
  atomicAdd(dst + 3, nm * xv.w);
}

// ---------------- fused gates + output ----------------
// z = sigmoid(x@Wx0[0] + Tx@Wx1[0] + bx[0] + bh[0])
// h = tanh   (x@Wx0[2] + Tx@Wx1[2] + bx[2] + bh[2])
// out = sum_k (1-z_k)*h_k*Wlin_k + blin
__global__ void __launch_bounds__(THREADS)
gate_kernel(const float* __restrict__ x, const float* __restrict__ Tx,
            const float* __restrict__ Wx0, const float* __restrict__ Wx1,
            const float* __restrict__ bx, const float* __restrict__ bh,
            const float* __restrict__ Wlin, const float* __restrict__ blin,
            float* __restrict__ out, int n) {
  __shared__ float sW[4 * 2048];  // [Wz0 | Wz1 | Wt0 | Wt1], each [32][64]
  __shared__ float sbz[64], sbt[64], swl[64];
  int tid = threadIdx.x;
  for (int i = tid; i < 2048; i += THREADS) {
    sW[i]        = Wx0[i];          // gate 0 (Z), W for x
    sW[2048 + i] = Wx1[i];          // gate 0 (Z), W for Tx
    sW[4096 + i] = Wx0[4096 + i];   // gate 2 (Ht), W for x
    sW[6144 + i] = Wx1[4096 + i];   // gate 2 (Ht), W for Tx
  }
  if (tid < 64) {
    sbz[tid] = bx[tid] + bh[tid];            // bx[0] + bh[0]
    sbt[tid] = bx[128 + tid] + bh[128 + tid];// bx[2] + bh[2]
    swl[tid] = Wlin[tid];
  }
  __syncthreads();

  int node = blockIdx.x * THREADS + tid;
  if (node >= n) return;

  float xv[32], tv[32];
  const float4* xp = (const float4*)(x + (long)node * 32);
  const float4* tp = (const float4*)(Tx + (long)node * 32);
#pragma unroll
  for (int i = 0; i < 8; i++) {
    float4 a = xp[i];
    float4 b = tp[i];
    xv[4 * i + 0] = a.x; xv[4 * i + 1] = a.y; xv[4 * i + 2] = a.z; xv[4 * i + 3] = a.w;
    tv[4 * i + 0] = b.x; tv[4 * i + 1] = b.y; tv[4 * i + 2] = b.z; tv[4 * i + 3] = b.w;
  }

  float oacc = 0.0f;
#pragma unroll 1
  for (int k0 = 0; k0 < 64; k0 += 4) {
    float az0 = sbz[k0], az1 = sbz[k0 + 1], az2 = sbz[k0 + 2], az3 = sbz[k0 + 3];
    float at0 = sbt[k0], at1 = sbt[k0 + 1], at2 = sbt[k0 + 2], at3 = sbt[k0 + 3];
#pragma unroll
    for (int f = 0; f < 32; f++) {   // full unroll keeps xv/tv in registers
      float4 wz0 = *(const float4*)&sW[f * 64 + k0];
      float4 wz1 = *(const float4*)&sW[2048 + f * 64 + k0];
      float4 wt0 = *(const float4*)&sW[4096 + f * 64 + k0];
      float4 wt1 = *(const float4*)&sW[6144 + f * 64 + k0];
      float xf = xv[f], tf = tv[f];
      az0 += xf * wz0.x + tf * wz1.x;
      az1 += xf * wz0.y + tf * wz1.y;
      az2 += xf * wz0.z + tf * wz1.z;
      az3 += xf * wz0.w + tf * wz1.w;
      at0 += xf * wt0.x + tf * wt1.x;
      at1 += xf * wt0.y + tf * wt1.y;
      at2 += xf * wt0.z + tf * wt1.z;
      at3 += xf * wt0.w + tf * wt1.w;
    }
    float z0 = 1.0f / (1.0f + expf(-az0));
    float z1 = 1.0f / (1.0f + expf(-az1));
    float z2 = 1.0f / (1.0f + expf(-az2));
    float z3 = 1.0f / (1.0f + expf(-az3));
    oacc += (1.0f - z0) * tanhf(at0) * swl[k0];
    oacc += (1.0f - z1) * tanhf(at1) * swl[k0 + 1];
    oacc += (1.0f - z2) * tanhf(at2) * swl[k0 + 2];
    oacc += (1.0f - z3) * tanhf(at3) * swl[k0 + 3];
  }
  out[node] = oacc + blin[0];
}

extern "C" void kernel_launch(void* const* d_in, const int* in_sizes, int n_in,
                              void* d_out, int out_size, void* d_ws, size_t ws_size,
                              hipStream_t stream) {
  const float* x    = (const float*)d_in[0];
  const float* ew   = (const float*)d_in[1];
  const float* Wx0  = (const float*)d_in[2];
  const float* Wx1  = (const float*)d_in[3];
  const float* bx   = (const float*)d_in[4];
  const float* bh   = (const float*)d_in[7];
  const float* Wlin = (const float*)d_in[8];
  const float* blin = (const float*)d_in[9];
  const int*   ei   = (const int*)d_in[10];

  int N = in_sizes[0] / 32;
  int E = in_sizes[1];
  const int* row = ei;
  const int* col = ei + E;

  float* Tx  = (float*)d_ws;             // N*32 floats
  float* deg = Tx + (size_t)N * 32;      // N floats (becomes disq in place)
  float* nrm = deg + N;                  // E floats
  float* out = (float*)d_out;

  long nz = (long)N * 32 + N;
  zero_kernel<<<512, THREADS, 0, stream>>>(Tx, nz);
  deg_kernel<<<(E + THREADS - 1) / THREADS, THREADS, 0, stream>>>(ew, row, deg, E);
  disq_kernel<<<(N + THREADS - 1) / THREADS, THREADS, 0, stream>>>(deg, N);
  norm_kernel<<<(E + THREADS - 1) / THREADS, THREADS, 0, stream>>>(ew, row, col, deg, nrm, E);
  long E8 = (long)E * 8;
  scatter_kernel<<<(int)((E8 + THREADS - 1) / THREADS), THREADS, 0, stream>>>(x, nrm, row, col, Tx, E8);
  gate_kernel<<<(N + THREADS - 1) / THREADS, THREADS, 0, stream>>>(x, Tx, Wx0, Wx1, bx, bh, Wlin, blin, out, N);
}

// Round 2
// 648.110 us; speedup vs baseline: 1.4706x; 1.4706x over previous
//
#include <hip/hip_runtime.h>

#define THREADS 256
#define SCAN_THREADS 1024

// ---------------- zero a word region ----------------
__global__ void zero_kernel(float* __restrict__ p, long n) {
  long i = (long)blockIdx.x * blockDim.x + threadIdx.x;
  long stride = (long)gridDim.x * blockDim.x;
  for (; i < n; i += stride) p[i] = 0.0f;
}

// ---------------- deg[row] += w ; hist[col]++ ----------------
__global__ void deg_hist_kernel(const float* __restrict__ w, const int* __restrict__ row,
                                const int* __restrict__ col, float* __restrict__ deg,
                                int* __restrict__ off, int E) {
  int e = blockIdx.x * blockDim.x + threadIdx.x;
  if (e < E) {
    atomicAdd(&deg[row[e]], w[e]);
    atomicAdd(&off[col[e]], 1);
  }
}

// ---------------- exclusive scan of hist (50K bins) + disq in place ----------------
__global__ void __launch_bounds__(SCAN_THREADS)
scan_disq_kernel(float* __restrict__ deg, int* __restrict__ off, int n) {
  __shared__ int stot[SCAN_THREADS];
  int t = threadIdx.x;
  int per = (n + SCAN_THREADS - 1) / SCAN_THREADS;
  int b0 = t * per;
  int b1 = min(b0 + per, n);
  int s = 0;
  for (int i = b0; i < b1; i++) s += off[i];
  stot[t] = s;
  for (int i = b0; i < b1; i++) {
    float d = deg[i];
    deg[i] = (d > 0.0f) ? rsqrtf(d) : 0.0f;   // deg -> disq in place
  }
  __syncthreads();
  for (int d = 1; d < SCAN_THREADS; d <<= 1) {
    int v = (t >= d) ? stot[t - d] : 0;
    __syncthreads();
    stot[t] += v;
    __syncthreads();
  }
  int run = (t == 0) ? 0 : stot[t - 1];       // exclusive base for this thread's bins
  for (int i = b0; i < b1; i++) {
    int c = off[i];
    off[i] = run;
    run += c;
  }
}

// ---------------- scatter edges into col-buckets: pairs[p] = (row, norm) ----------------
// After this kernel off[c] = end of bucket c (start of bucket c+1).
__global__ void bucket_kernel(const float* __restrict__ w, const int* __restrict__ row,
                              const int* __restrict__ col, const float* __restrict__ disq,
                              int* __restrict__ off, int2* __restrict__ pairs, int E) {
  int e = blockIdx.x * blockDim.x + threadIdx.x;
  if (e >= E) return;
  int r = row[e];
  int c = col[e];
  float v = -w[e] * disq[r] * disq[c];
  int p = atomicAdd(&off[c], 1);
  pairs[p] = make_int2(r, __float_as_int(v));
}

// ---------------- gather: one wave per node, no atomics ----------------
__global__ void gather_kernel(const float* __restrict__ x, const int* __restrict__ off,
                              const int2* __restrict__ pairs, float* __restrict__ Tx, int n) {
  int wid = (int)(((long)blockIdx.x * blockDim.x + threadIdx.x) >> 6);
  if (wid >= n) return;
  int lane = threadIdx.x & 63;
  int s = lane >> 5, f = lane & 31;
  int start = wid ? off[wid - 1] : 0;
  int end = off[wid];
  float acc = 0.0f;
  for (int i = start + s; i < end; i += 2) {
    int2 pv = pairs[i];
    acc += __int_as_float(pv.y) * x[(long)pv.x * 32 + f];
  }
  acc += __shfl_xor(acc, 32);
  if (s == 0) Tx[(long)wid * 32 + f] = acc;
}

// ---------------- fallback kernels (round-1 atomic path) ----------------
__global__ void disq_kernel(float* __restrict__ deg, int n) {
  int i = blockIdx.x * blockDim.x + threadIdx.x;
  if (i < n) {
    float d = deg[i];
    deg[i] = (d > 0.0f) ? rsqrtf(d) : 0.0f;
  }
}

__global__ void deg_kernel(const float* __restrict__ w, const int* __restrict__ row,
                           float* __restrict__ deg, int E) {
  int e = blockIdx.x * blockDim.x + threadIdx.x;
  if (e < E) atomicAdd(&deg[row[e]], w[e]);
}

__global__ void norm_kernel(const float* __restrict__ w, const int* __restrict__ row,
                            const int* __restrict__ col, const float* __restrict__ disq,
                            float* __restrict__ nrm, int E) {
  int e = blockIdx.x * blockDim.x + threadIdx.x;
  if (e < E) nrm[e] = -w[e] * disq[row[e]] * disq[col[e]];
}

__global__ void scatter_kernel(const float* __restrict__ x, const float* __restrict__ nrm,
                               const int* __restrict__ row, const int* __restrict__ col,
                               float* __restrict__ Tx, long E8) {
  long t = (long)blockIdx.x * blockDim.x + threadIdx.x;
  if (t >= E8) return;
  long e = t >> 3;
  int j = (int)(t & 7);
  int r = row[e];
  int c = col[e];
  float nm = nrm[e];
  float4 xv = *(const float4*)(x + (long)r * 32 + j * 4);
  float* dst = Tx + (long)c * 32 + j * 4;
  atomicAdd(dst + 0, nm * xv.x);
  atomicAdd(dst + 1, nm * xv.y);
  atomicAdd(dst + 2, nm * xv.z);
  atomicAdd(dst + 3, nm * xv.w);
}

// ---------------- fused gates + output (unchanged, verified) ----------------
__global__ void __launch_bounds__(THREADS)
gate_kernel(const float* __restrict__ x, const float* __restrict__ Tx,
            const float* __restrict__ Wx0, const float* __restrict__ Wx1,
            const float* __restrict__ bx, const float* __restrict__ bh,
            const float* __restrict__ Wlin, const float* __restrict__ blin,
            float* __restrict__ out, int n) {
  __shared__ float sW[4 * 2048];  // [Wz0 | Wz1 | Wt0 | Wt1], each [32][64]
  __shared__ float sbz[64], sbt[64], swl[64];
  int tid = threadIdx.x;
  for (int i = tid; i < 2048; i += THREADS) {
    sW[i]        = Wx0[i];
    sW[2048 + i] = Wx1[i];
    sW[4096 + i] = Wx0[4096 + i];
    sW[6144 + i] = Wx1[4096 + i];
  }
  if (tid < 64) {
    sbz[tid] = bx[tid] + bh[tid];
    sbt[tid] = bx[128 + tid] + bh[128 + tid];
    swl[tid] = Wlin[tid];
  }
  __syncthreads();

  int node = blockIdx.x * THREADS + tid;
  if (node >= n) return;

  float xv[32], tv[32];
  const float4* xp = (const float4*)(x + (long)node * 32);
  const float4* tp = (const float4*)(Tx + (long)node * 32);
#pragma unroll
  for (int i = 0; i < 8; i++) {
    float4 a = xp[i];
    float4 b = tp[i];
    xv[4 * i + 0] = a.x; xv[4 * i + 1] = a.y; xv[4 * i + 2] = a.z; xv[4 * i + 3] = a.w;
    tv[4 * i + 0] = b.x; tv[4 * i + 1] = b.y; tv[4 * i + 2] = b.z; tv[4 * i + 3] = b.w;
  }

  float oacc = 0.0f;
#pragma unroll 1
  for (int k0 = 0; k0 < 64; k0 += 4) {
    float az0 = sbz[k0], az1 = sbz[k0 + 1], az2 = sbz[k0 + 2], az3 = sbz[k0 + 3];
    float at0 = sbt[k0], at1 = sbt[k0 + 1], at2 = sbt[k0 + 2], at3 = sbt[k0 + 3];
#pragma unroll
    for (int f = 0; f < 32; f++) {
      float4 wz0 = *(const float4*)&sW[f * 64 + k0];
      float4 wz1 = *(const float4*)&sW[2048 + f * 64 + k0];
      float4 wt0 = *(const float4*)&sW[4096 + f * 64 + k0];
      float4 wt1 = *(const float4*)&sW[6144 + f * 64 + k0];
      float xf = xv[f], tf = tv[f];
      az0 += xf * wz0.x + tf * wz1.x;
      az1 += xf * wz0.y + tf * wz1.y;
      az2 += xf * wz0.z + tf * wz1.z;
      az3 += xf * wz0.w + tf * wz1.w;
      at0 += xf * wt0.x + tf * wt1.x;
      at1 += xf * wt0.y + tf * wt1.y;
      at2 += xf * wt0.z + tf * wt1.z;
      at3 += xf * wt0.w + tf * wt1.w;
    }
    float z0 = 1.0f / (1.0f + expf(-az0));
    float z1 = 1.0f / (1.0f + expf(-az1));
    float z2 = 1.0f / (1.0f + expf(-az2));
    float z3 = 1.0f / (1.0f + expf(-az3));
    oacc += (1.0f - z0) * tanhf(at0) * swl[k0];
    oacc += (1.0f - z1) * tanhf(at1) * swl[k0 + 1];
    oacc += (1.0f - z2) * tanhf(at2) * swl[k0 + 2];
    oacc += (1.0f - z3) * tanhf(at3) * swl[k0 + 3];
  }
  out[node] = oacc + blin[0];
}

extern "C" void kernel_launch(void* const* d_in, const int* in_sizes, int n_in,
                              void* d_out, int out_size, void* d_ws, size_t ws_size,
                              hipStream_t stream) {
  const float* x    = (const float*)d_in[0];
  const float* ew   = (const float*)d_in[1];
  const float* Wx0  = (const float*)d_in[2];
  const float* Wx1  = (const float*)d_in[3];
  const float* bx   = (const float*)d_in[4];
  const float* bh   = (const float*)d_in[7];
  const float* Wlin = (const float*)d_in[8];
  const float* blin = (const float*)d_in[9];
  const int*   ei   = (const int*)d_in[10];

  int N = in_sizes[0] / 32;
  int E = in_sizes[1];
  const int* row = ei;
  const int* col = ei + E;
  float* out = (float*)d_out;

  // sort-based layout: [Tx N*32][deg/disq N][off N][pad][pairs E int2]
  float* Tx  = (float*)d_ws;
  float* deg = Tx + (size_t)N * 32;
  int*   off = (int*)(deg + N);
  size_t padElems = (size_t)N * 32 + N + N;
  if (padElems & 1) padElems++;
  int2* pairs = (int2*)((float*)d_ws + padElems);
  size_t need = padElems * 4 + (size_t)E * 8;

  if (ws_size >= need) {
    // ---- sort + gather path (no f32 scatter atomics) ----
    zero_kernel<<<128, THREADS, 0, stream>>>(deg, (long)N * 2);  // deg + off
    deg_hist_kernel<<<(E + THREADS - 1) / THREADS, THREADS, 0, stream>>>(ew, row, col, deg, off, E);
    scan_disq_kernel<<<1, SCAN_THREADS, 0, stream>>>(deg, off, N);
    bucket_kernel<<<(E + THREADS - 1) / THREADS, THREADS, 0, stream>>>(ew, row, col, deg, off, pairs, E);
    long tthreads = (long)N * 64;
    gather_kernel<<<(int)((tthreads + THREADS - 1) / THREADS), THREADS, 0, stream>>>(x, off, pairs, Tx, N);
    gate_kernel<<<(N + THREADS - 1) / THREADS, THREADS, 0, stream>>>(x, Tx, Wx0, Wx1, bx, bh, Wlin, blin, out, N);
  } else {
    // ---- fallback: round-1 atomic scatter path ----
    float* nrm = (float*)(deg + N);  // E floats
    long nz = (long)N * 32 + N;
    zero_kernel<<<512, THREADS, 0, stream>>>(Tx, nz);
    deg_kernel<<<(E + THREADS - 1) / THREADS, THREADS, 0, stream>>>(ew, row, deg, E);
    disq_kernel<<<(N + THREADS - 1) / THREADS, THREADS, 0, stream>>>(deg, N);
    norm_kernel<<<(E + THREADS - 1) / THREADS, THREADS, 0, stream>>>(ew, row, col, deg, nrm, E);
    long E8 = (long)E * 8;
    scatter_kernel<<<(int)((E8 + THREADS - 1) / THREADS), THREADS, 0, stream>>>(x, nrm, row, col, Tx, E8);
    gate_kernel<<<(N + THREADS - 1) / THREADS, THREADS, 0, stream>>>(x, Tx, Wx0, Wx1, bx, bh, Wlin, blin, out, N);
  }
}

// Round 3
// 453.693 us; speedup vs baseline: 2.1008x; 1.4285x over previous
//
#include <hip/hip_runtime.h>

#define THREADS 256
#define SCAN_THREADS 1024

// ---------------- zero a word region ----------------
__global__ void zero_kernel(float* __restrict__ p, long n) {
  long i = (long)blockIdx.x * blockDim.x + threadIdx.x;
  long stride = (long)gridDim.x * blockDim.x;
  for (; i < n; i += stride) p[i] = 0.0f;
}

// ---------------- deg[row] += w ; hist[col]++ ----------------
__global__ void deg_hist_kernel(const float* __restrict__ w, const int* __restrict__ row,
                                const int* __restrict__ col, float* __restrict__ deg,
                                int* __restrict__ off, int E) {
  int e = blockIdx.x * blockDim.x + threadIdx.x;
  if (e < E) {
    atomicAdd(&deg[row[e]], w[e]);
    atomicAdd(&off[col[e]], 1);
  }
}

// ---------------- exclusive scan of hist (50K bins) + disq in place ----------------
__global__ void __launch_bounds__(SCAN_THREADS)
scan_disq_kernel(float* __restrict__ deg, int* __restrict__ off, int n) {
  __shared__ int stot[SCAN_THREADS];
  int t = threadIdx.x;
  int per = (n + SCAN_THREADS - 1) / SCAN_THREADS;
  int b0 = t * per;
  int b1 = min(b0 + per, n);
  int s = 0;
  for (int i = b0; i < b1; i++) s += off[i];
  stot[t] = s;
  for (int i = b0; i < b1; i++) {
    float d = deg[i];
    deg[i] = (d > 0.0f) ? rsqrtf(d) : 0.0f;   // deg -> disq in place
  }
  __syncthreads();
  for (int d = 1; d < SCAN_THREADS; d <<= 1) {
    int v = (t >= d) ? stot[t - d] : 0;
    __syncthreads();
    stot[t] += v;
    __syncthreads();
  }
  int run = (t == 0) ? 0 : stot[t - 1];       // exclusive base for this thread's bins
  for (int i = b0; i < b1; i++) {
    int c = off[i];
    off[i] = run;
    run += c;
  }
}

// ---------------- scatter edges into col-buckets: pairs[p] = (row, norm) ----------------
__global__ void bucket_kernel(const float* __restrict__ w, const int* __restrict__ row,
                              const int* __restrict__ col, const float* __restrict__ disq,
                              int* __restrict__ off, int2* __restrict__ pairs, int E) {
  int e = blockIdx.x * blockDim.x + threadIdx.x;
  if (e >= E) return;
  int r = row[e];
  int c = col[e];
  float v = -w[e] * disq[r] * disq[c];
  int p = atomicAdd(&off[c], 1);
  pairs[p] = make_int2(r, __float_as_int(v));
}

// ---------------- gather: one wave per node, 8 edge-slots, no atomics ----------------
__global__ void gather_kernel(const float* __restrict__ x, const int* __restrict__ off,
                              const int2* __restrict__ pairs, float* __restrict__ Tx, int n) {
  int wid = (int)(((long)blockIdx.x * blockDim.x + threadIdx.x) >> 6);
  if (wid >= n) return;
  int lane = threadIdx.x & 63;
  int slot = lane >> 3;     // 0..7  -> 8 edges in flight
  int f4 = lane & 7;        // float4 chunk of the 32-wide feature row
  int start = wid ? off[wid - 1] : 0;
  int end = off[wid];
  float4 acc = make_float4(0.f, 0.f, 0.f, 0.f);
  for (int i = start + slot; i < end; i += 8) {
    int2 pv = pairs[i];
    float v = __int_as_float(pv.y);
    float4 xr = *(const float4*)(x + (long)pv.x * 32 + f4 * 4);
    acc.x += v * xr.x;
    acc.y += v * xr.y;
    acc.z += v * xr.z;
    acc.w += v * xr.w;
  }
#pragma unroll
  for (int d = 8; d < 64; d <<= 1) {
    acc.x += __shfl_xor(acc.x, d);
    acc.y += __shfl_xor(acc.y, d);
    acc.z += __shfl_xor(acc.z, d);
    acc.w += __shfl_xor(acc.w, d);
  }
  if (slot == 0) *(float4*)(Tx + (long)wid * 32 + f4 * 4) = acc;
}

// ---------------- fused gates + output: one wave per node, lane = output k ----------------
// az[k] = sum_f x[f]*Wx0[0][f][k] + Tx[f]*Wx1[0][f][k] + bx[0][k] + bh[0][k]
// at[k] = sum_f x[f]*Wx0[2][f][k] + Tx[f]*Wx1[2][f][k] + bx[2][k] + bh[2][k]
// out[node] = sum_k (1-sigmoid(az))*tanh(at)*Wlin[k] + blin
__global__ void __launch_bounds__(THREADS, 2)
gate_kernel(const float* __restrict__ x, const float* __restrict__ Tx,
            const float* __restrict__ Wx0, const float* __restrict__ Wx1,
            const float* __restrict__ bx, const float* __restrict__ bh,
            const float* __restrict__ Wlin, const float* __restrict__ blin,
            float* __restrict__ out, int n) {
  int lane = threadIdx.x & 63;
  int wave = blockIdx.x * (THREADS / 64) + (threadIdx.x >> 6);
  int nwaves = gridDim.x * (THREADS / 64);

  // per-lane weight columns (k = lane), register-resident, amortized via grid-stride
  float wz0[32], wz1[32], wt0[32], wt1[32];
#pragma unroll
  for (int f = 0; f < 32; f++) {
    wz0[f] = Wx0[f * 64 + lane];
    wz1[f] = Wx1[f * 64 + lane];
    wt0[f] = Wx0[4096 + f * 64 + lane];
    wt1[f] = Wx1[4096 + f * 64 + lane];
  }
  float bz = bx[lane] + bh[lane];
  float bt = bx[128 + lane] + bh[128 + lane];
  float wl = Wlin[lane];
  float bl = blin[0];

  for (int node = wave; node < n; node += nwaves) {
    const float4* xp = (const float4*)(x + (long)node * 32);
    const float4* tp = (const float4*)(Tx + (long)node * 32);
    float azx = 0.f, azt = 0.f, atx = 0.f, att = 0.f;
#pragma unroll
    for (int c = 0; c < 8; c++) {
      float4 xa = xp[c];   // lane-uniform broadcast load
      float4 ta = tp[c];
      azx += xa.x * wz0[4 * c + 0];
      azx += xa.y * wz0[4 * c + 1];
      azx += xa.z * wz0[4 * c + 2];
      azx += xa.w * wz0[4 * c + 3];
      azt += ta.x * wz1[4 * c + 0];
      azt += ta.y * wz1[4 * c + 1];
      azt += ta.z * wz1[4 * c + 2];
      azt += ta.w * wz1[4 * c + 3];
      atx += xa.x * wt0[4 * c + 0];
      atx += xa.y * wt0[4 * c + 1];
      atx += xa.z * wt0[4 * c + 2];
      atx += xa.w * wt0[4 * c + 3];
      att += ta.x * wt1[4 * c + 0];
      att += ta.y * wt1[4 * c + 1];
      att += ta.z * wt1[4 * c + 2];
      att += ta.w * wt1[4 * c + 3];
    }
    float az = azx + azt + bz;
    float at = atx + att + bt;
    float zk = 1.0f / (1.0f + __expf(-az));
    float contrib = (1.0f - zk) * tanhf(at) * wl;
#pragma unroll
    for (int d = 1; d < 64; d <<= 1) contrib += __shfl_xor(contrib, d);
    if (lane == 0) out[node] = contrib + bl;
  }
}

extern "C" void kernel_launch(void* const* d_in, const int* in_sizes, int n_in,
                              void* d_out, int out_size, void* d_ws, size_t ws_size,
                              hipStream_t stream) {
  const float* x    = (const float*)d_in[0];
  const float* ew   = (const float*)d_in[1];
  const float* Wx0  = (const float*)d_in[2];
  const float* Wx1  = (const float*)d_in[3];
  const float* bx   = (const float*)d_in[4];
  const float* bh   = (const float*)d_in[7];
  const float* Wlin = (const float*)d_in[8];
  const float* blin = (const float*)d_in[9];
  const int*   ei   = (const int*)d_in[10];

  int N = in_sizes[0] / 32;
  int E = in_sizes[1];
  const int* row = ei;
  const int* col = ei + E;
  float* out = (float*)d_out;

  // layout: [Tx N*32][deg/disq N][off N][pad][pairs E int2]
  float* Tx  = (float*)d_ws;
  float* deg = Tx + (size_t)N * 32;
  int*   off = (int*)(deg + N);
  size_t padElems = (size_t)N * 32 + N + N;
  if (padElems & 1) padElems++;
  int2* pairs = (int2*)((float*)d_ws + padElems);

  zero_kernel<<<128, THREADS, 0, stream>>>(deg, (long)N * 2);  // deg + off
  deg_hist_kernel<<<(E + THREADS - 1) / THREADS, THREADS, 0, stream>>>(ew, row, col, deg, off, E);
  scan_disq_kernel<<<1, SCAN_THREADS, 0, stream>>>(deg, off, N);
  bucket_kernel<<<(E + THREADS - 1) / THREADS, THREADS, 0, stream>>>(ew, row, col, deg, off, pairs, E);
  long tthreads = (long)N * 64;
  gather_kernel<<<(int)((tthreads + THREADS - 1) / THREADS), THREADS, 0, stream>>>(x, off, pairs, Tx, N);
  gate_kernel<<<512, THREADS, 0, stream>>>(x, Tx, Wx0, Wx1, bx, bh, Wlin, blin, out, N);
}

// Round 4
// 313.947 us; speedup vs baseline: 3.0358x; 1.4451x over previous
//
#include <hip/hip_runtime.h>

#define THREADS 256
#define SB 1024

// ---------------- zero a word region ----------------
__global__ void zero_kernel(float* __restrict__ p, long n) {
  long i = (long)blockIdx.x * blockDim.x + threadIdx.x;
  long stride = (long)gridDim.x * blockDim.x;
  for (; i < n; i += stride) p[i] = 0.0f;
}

// ---------------- deg[row] += w ; hist[col]++ ----------------
__global__ void deg_hist_kernel(const float* __restrict__ w, const int* __restrict__ row,
                                const int* __restrict__ col, float* __restrict__ deg,
                                int* __restrict__ off, int E) {
  int e = blockIdx.x * blockDim.x + threadIdx.x;
  if (e < E) {
    atomicAdd(&deg[row[e]], w[e]);
    atomicAdd(&off[col[e]], 1);
  }
}

// ---------------- device-wide exclusive scan, stage 1: per-block ----------------
__global__ void __launch_bounds__(SB)
scan_blocks_kernel(int* __restrict__ off, int* __restrict__ bsum, int n) {
  __shared__ int s[SB];
  int t = threadIdx.x;
  int i = blockIdx.x * SB + t;
  int v = (i < n) ? off[i] : 0;
  s[t] = v;
  __syncthreads();
  for (int d = 1; d < SB; d <<= 1) {
    int u = (t >= d) ? s[t - d] : 0;
    __syncthreads();
    s[t] += u;
    __syncthreads();
  }
  if (i < n) off[i] = s[t] - v;                 // exclusive within block
  if (t == SB - 1) bsum[blockIdx.x] = s[SB - 1]; // block total
}

// ---------------- stage 2: exclusive scan of block totals (nb <= 1024) ----------------
__global__ void __launch_bounds__(SB)
scan_top_kernel(int* __restrict__ bsum, int nb) {
  __shared__ int s[SB];
  int t = threadIdx.x;
  int v = (t < nb) ? bsum[t] : 0;
  s[t] = v;
  __syncthreads();
  for (int d = 1; d < SB; d <<= 1) {
    int u = (t >= d) ? s[t - d] : 0;
    __syncthreads();
    s[t] += u;
    __syncthreads();
  }
  if (t < nb) bsum[t] = s[t] - v;               // exclusive
}

// ---------------- stage 3: add block offsets; fuse deg -> rsqrt(deg) ----------------
__global__ void scan_add_disq_kernel(int* __restrict__ off, const int* __restrict__ bsum,
                                     float* __restrict__ deg, int n) {
  int i = blockIdx.x * blockDim.x + threadIdx.x;
  if (i < n) {
    off[i] += bsum[i >> 10];
    float d = deg[i];
    deg[i] = (d > 0.0f) ? rsqrtf(d) : 0.0f;
  }
}

// ---------------- scatter edges into col-buckets: pairs[p] = (row, norm) ----------------
// After this kernel off[c] = end of bucket c.
__global__ void bucket_kernel(const float* __restrict__ w, const int* __restrict__ row,
                              const int* __restrict__ col, const float* __restrict__ disq,
                              int* __restrict__ off, int2* __restrict__ pairs, int E) {
  int e = blockIdx.x * blockDim.x + threadIdx.x;
  if (e >= E) return;
  int r = row[e];
  int c = col[e];
  float v = -w[e] * disq[r] * disq[c];
  int p = atomicAdd(&off[c], 1);
  pairs[p] = make_int2(r, __float_as_int(v));
}

// ---------------- gather: one wave per node, 8 edge-slots, no atomics ----------------
__global__ void gather_kernel(const float* __restrict__ x, const int* __restrict__ off,
                              const int2* __restrict__ pairs, float* __restrict__ Tx, int n) {
  int wid = (int)(((long)blockIdx.x * blockDim.x + threadIdx.x) >> 6);
  if (wid >= n) return;
  int lane = threadIdx.x & 63;
  int slot = lane >> 3;     // 0..7  -> 8 edges in flight
  int f4 = lane & 7;        // float4 chunk of the 32-wide feature row
  int start = wid ? off[wid - 1] : 0;
  int end = off[wid];
  float4 acc = make_float4(0.f, 0.f, 0.f, 0.f);
  for (int i = start + slot; i < end; i += 8) {
    int2 pv = pairs[i];
    float v = __int_as_float(pv.y);
    float4 xr = *(const float4*)(x + (long)pv.x * 32 + f4 * 4);
    acc.x += v * xr.x;
    acc.y += v * xr.y;
    acc.z += v * xr.z;
    acc.w += v * xr.w;
  }
#pragma unroll
  for (int d = 8; d < 64; d <<= 1) {
    acc.x += __shfl_xor(acc.x, d);
    acc.y += __shfl_xor(acc.y, d);
    acc.z += __shfl_xor(acc.z, d);
    acc.w += __shfl_xor(acc.w, d);
  }
  if (slot == 0) *(float4*)(Tx + (long)wid * 32 + f4 * 4) = acc;
}

// ---------------- fused gates + output: one wave per node, lane = output k ----------------
__global__ void __launch_bounds__(THREADS, 2)
gate_kernel(const float* __restrict__ x, const float* __restrict__ Tx,
            const float* __restrict__ Wx0, const float* __restrict__ Wx1,
            const float* __restrict__ bx, const float* __restrict__ bh,
            const float* __restrict__ Wlin, const float* __restrict__ blin,
            float* __restrict__ out, int n) {
  int lane = threadIdx.x & 63;
  int wave = blockIdx.x * (THREADS / 64) + (threadIdx.x >> 6);
  int nwaves = gridDim.x * (THREADS / 64);

  float wz0[32], wz1[32], wt0[32], wt1[32];
#pragma unroll
  for (int f = 0; f < 32; f++) {
    wz0[f] = Wx0[f * 64 + lane];
    wz1[f] = Wx1[f * 64 + lane];
    wt0[f] = Wx0[4096 + f * 64 + lane];
    wt1[f] = Wx1[4096 + f * 64 + lane];
  }
  float bz = bx[lane] + bh[lane];
  float bt = bx[128 + lane] + bh[128 + lane];
  float wl = Wlin[lane];
  float bl = blin[0];

  for (int node = wave; node < n; node += nwaves) {
    const float4* xp = (const float4*)(x + (long)node * 32);
    const float4* tp = (const float4*)(Tx + (long)node * 32);
    float azx = 0.f, azt = 0.f, atx = 0.f, att = 0.f;
#pragma unroll
    for (int c = 0; c < 8; c++) {
      float4 xa = xp[c];
      float4 ta = tp[c];
      azx += xa.x * wz0[4 * c + 0];
      azx += xa.y * wz0[4 * c + 1];
      azx += xa.z * wz0[4 * c + 2];
      azx += xa.w * wz0[4 * c + 3];
      azt += ta.x * wz1[4 * c + 0];
      azt += ta.y * wz1[4 * c + 1];
      azt += ta.z * wz1[4 * c + 2];
      azt += ta.w * wz1[4 * c + 3];
      atx += xa.x * wt0[4 * c + 0];
      atx += xa.y * wt0[4 * c + 1];
      atx += xa.z * wt0[4 * c + 2];
      atx += xa.w * wt0[4 * c + 3];
      att += ta.x * wt1[4 * c + 0];
      att += ta.y * wt1[4 * c + 1];
      att += ta.z * wt1[4 * c + 2];
      att += ta.w * wt1[4 * c + 3];
    }
    float az = azx + azt + bz;
    float at = atx + att + bt;
    float zk = 1.0f / (1.0f + __expf(-az));
    float contrib = (1.0f - zk) * tanhf(at) * wl;
#pragma unroll
    for (int d = 1; d < 64; d <<= 1) contrib += __shfl_xor(contrib, d);
    if (lane == 0) out[node] = contrib + bl;
  }
}

extern "C" void kernel_launch(void* const* d_in, const int* in_sizes, int n_in,
                              void* d_out, int out_size, void* d_ws, size_t ws_size,
                              hipStream_t stream) {
  const float* x    = (const float*)d_in[0];
  const float* ew   = (const float*)d_in[1];
  const float* Wx0  = (const float*)d_in[2];
  const float* Wx1  = (const float*)d_in[3];
  const float* bx   = (const float*)d_in[4];
  const float* bh   = (const float*)d_in[7];
  const float* Wlin = (const float*)d_in[8];
  const float* blin = (const float*)d_in[9];
  const int*   ei   = (const int*)d_in[10];

  int N = in_sizes[0] / 32;
  int E = in_sizes[1];
  const int* row = ei;
  const int* col = ei + E;
  float* out = (float*)d_out;

  // layout: [Tx N*32][deg/disq N][off N][pad][pairs E int2][bsum nb]
  float* Tx  = (float*)d_ws;
  float* deg = Tx + (size_t)N * 32;
  int*   off = (int*)(deg + N);
  size_t padElems = (size_t)N * 32 + N + N;
  if (padElems & 1) padElems++;
  int2* pairs = (int2*)((float*)d_ws + padElems);
  int nb = (N + SB - 1) / SB;
  int* bsum = (int*)(pairs + E);

  zero_kernel<<<128, THREADS, 0, stream>>>(deg, (long)N * 2);  // deg + off
  deg_hist_kernel<<<(E + THREADS - 1) / THREADS, THREADS, 0, stream>>>(ew, row, col, deg, off, E);
  scan_blocks_kernel<<<nb, SB, 0, stream>>>(off, bsum, N);
  scan_top_kernel<<<1, SB, 0, stream>>>(bsum, nb);
  scan_add_disq_kernel<<<(N + THREADS - 1) / THREADS, THREADS, 0, stream>>>(off, bsum, deg, N);
  bucket_kernel<<<(E + THREADS - 1) / THREADS, THREADS, 0, stream>>>(ew, row, col, deg, off, pairs, E);
  long tthreads = (long)N * 64;
  gather_kernel<<<(int)((tthreads + THREADS - 1) / THREADS), THREADS, 0, stream>>>(x, off, pairs, Tx, N);
  gate_kernel<<<512, THREADS, 0, stream>>>(x, Tx, Wx0, Wx1, bx, bh, Wlin, blin, out, N);
}

// Round 5
// 304.749 us; speedup vs baseline: 3.1275x; 1.0302x over previous
//
#include <hip/hip_runtime.h>

#define THREADS 256
#define SB 1024
#define KD 8   // deg replication (degR lives in dead Tx region, always 8)

// ---------------- zero word regions ----------------
__global__ void zero_kernel(int* __restrict__ p, long n) {
  long i = (long)blockIdx.x * blockDim.x + threadIdx.x;
  long stride = (long)gridDim.x * blockDim.x;
  for (; i < n; i += stride) p[i] = 0;
}

// ---------------- degR[k][row] += w ; offR[(col<<ks)|kh]++ ----------------
__global__ void deg_hist_kernel(const float* __restrict__ w, const int* __restrict__ row,
                                const int* __restrict__ col, float* __restrict__ degR,
                                int* __restrict__ offR, int E, int N, int khm, int ks) {
  int e = blockIdx.x * blockDim.x + threadIdx.x;
  if (e < E) {
    int kd = blockIdx.x & (KD - 1);
    atomicAdd(&degR[kd * N + row[e]], w[e]);
    int kh = blockIdx.x & khm;
    atomicAdd(&offR[(col[e] << ks) | kh], 1);
  }
}

// ---------------- device-wide exclusive scan, stage 1: per-block ----------------
__global__ void __launch_bounds__(SB)
scan_blocks_kernel(int* __restrict__ off, int* __restrict__ bsum, int n) {
  __shared__ int s[SB];
  int t = threadIdx.x;
  int i = blockIdx.x * SB + t;
  int v = (i < n) ? off[i] : 0;
  s[t] = v;
  __syncthreads();
  for (int d = 1; d < SB; d <<= 1) {
    int u = (t >= d) ? s[t - d] : 0;
    __syncthreads();
    s[t] += u;
    __syncthreads();
  }
  if (i < n) off[i] = s[t] - v;                  // exclusive within block
  if (t == SB - 1) bsum[blockIdx.x] = s[SB - 1]; // block total
}

// ---------------- stage 2: exclusive scan of block totals (nb <= 1024) ----------------
__global__ void __launch_bounds__(SB)
scan_top_kernel(int* __restrict__ bsum, int nb) {
  __shared__ int s[SB];
  int t = threadIdx.x;
  int v = (t < nb) ? bsum[t] : 0;
  s[t] = v;
  __syncthreads();
  for (int d = 1; d < SB; d <<= 1) {
    int u = (t >= d) ? s[t - d] : 0;
    __syncthreads();
    s[t] += u;
    __syncthreads();
  }
  if (t < nb) bsum[t] = s[t] - v;                // exclusive
}

// ---------------- stage 3: add block offsets; reduce degR -> disq ----------------
__global__ void scan_add_disq_kernel(int* __restrict__ off, const int* __restrict__ bsum,
                                     const float* __restrict__ degR, float* __restrict__ disq,
                                     int n2, int N) {
  int i = blockIdx.x * blockDim.x + threadIdx.x;
  if (i < n2) off[i] += bsum[i >> 10];
  if (i < N) {
    float d = 0.f;
#pragma unroll
    for (int k = 0; k < KD; k++) d += degR[k * N + i];
    disq[i] = (d > 0.0f) ? rsqrtf(d) : 0.0f;
  }
}

// ---------------- scatter edges into sub-buckets: pairs[p] = (row, norm) ----------------
// After this kernel offR[b] = end of sub-bin b.
__global__ void bucket_kernel(const float* __restrict__ w, const int* __restrict__ row,
                              const int* __restrict__ col, const float* __restrict__ disq,
                              int* __restrict__ offR, int2* __restrict__ pairs,
                              int E, int khm, int ks) {
  int e = blockIdx.x * blockDim.x + threadIdx.x;
  if (e >= E) return;
  int r = row[e];
  int c = col[e];
  float v = -w[e] * disq[r] * disq[c];
  int kh = blockIdx.x & khm;
  int p = atomicAdd(&offR[(c << ks) | kh], 1);
  pairs[p] = make_int2(r, __float_as_int(v));
}

// ---------------- gather: one wave per node, 8 edge-slots, no atomics ----------------
__global__ void gather_kernel(const float* __restrict__ x, const int* __restrict__ offR,
                              const int2* __restrict__ pairs, float* __restrict__ Tx,
                              int n, int khm, int ks) {
  int wid = (int)(((long)blockIdx.x * blockDim.x + threadIdx.x) >> 6);
  if (wid >= n) return;
  int lane = threadIdx.x & 63;
  int slot = lane >> 3;     // 0..7  -> 8 edges in flight
  int f4 = lane & 7;        // float4 chunk of the 32-wide feature row
  int start = wid ? offR[(wid << ks) - 1] : 0;
  int end = offR[(wid << ks) + khm];
  float4 acc = make_float4(0.f, 0.f, 0.f, 0.f);
  for (int i = start + slot; i < end; i += 8) {
    int2 pv = pairs[i];
    float v = __int_as_float(pv.y);
    float4 xr = *(const float4*)(x + (long)pv.x * 32 + f4 * 4);
    acc.x += v * xr.x;
    acc.y += v * xr.y;
    acc.z += v * xr.z;
    acc.w += v * xr.w;
  }
#pragma unroll
  for (int d = 8; d < 64; d <<= 1) {
    acc.x += __shfl_xor(acc.x, d);
    acc.y += __shfl_xor(acc.y, d);
    acc.z += __shfl_xor(acc.z, d);
    acc.w += __shfl_xor(acc.w, d);
  }
  if (slot == 0) *(float4*)(Tx + (long)wid * 32 + f4 * 4) = acc;
}

// ---------------- fused gates + output: one wave per node, lane = output k ----------------
__global__ void __launch_bounds__(THREADS, 2)
gate_kernel(const float* __restrict__ x, const float* __restrict__ Tx,
            const float* __restrict__ Wx0, const float* __restrict__ Wx1,
            const float* __restrict__ bx, const float* __restrict__ bh,
            const float* __restrict__ Wlin, const float* __restrict__ blin,
            float* __restrict__ out, int n) {
  int lane = threadIdx.x & 63;
  int wave = blockIdx.x * (THREADS / 64) + (threadIdx.x >> 6);
  int nwaves = gridDim.x * (THREADS / 64);

  float wz0[32], wz1[32], wt0[32], wt1[32];
#pragma unroll
  for (int f = 0; f < 32; f++) {
    wz0[f] = Wx0[f * 64 + lane];
    wz1[f] = Wx1[f * 64 + lane];
    wt0[f] = Wx0[4096 + f * 64 + lane];
    wt1[f] = Wx1[4096 + f * 64 + lane];
  }
  float bz = bx[lane] + bh[lane];
  float bt = bx[128 + lane] + bh[128 + lane];
  float wl = Wlin[lane];
  float bl = blin[0];

  for (int node = wave; node < n; node += nwaves) {
    const float4* xp = (const float4*)(x + (long)node * 32);
    const float4* tp = (const float4*)(Tx + (long)node * 32);
    float azx = 0.f, azt = 0.f, atx = 0.f, att = 0.f;
#pragma unroll
    for (int c = 0; c < 8; c++) {
      float4 xa = xp[c];
      float4 ta = tp[c];
      azx += xa.x * wz0[4 * c + 0];
      azx += xa.y * wz0[4 * c + 1];
      azx += xa.z * wz0[4 * c + 2];
      azx += xa.w * wz0[4 * c + 3];
      azt += ta.x * wz1[4 * c + 0];
      azt += ta.y * wz1[4 * c + 1];
      azt += ta.z * wz1[4 * c + 2];
      azt += ta.w * wz1[4 * c + 3];
      atx += xa.x * wt0[4 * c + 0];
      atx += xa.y * wt0[4 * c + 1];
      atx += xa.z * wt0[4 * c + 2];
      atx += xa.w * wt0[4 * c + 3];
      att += ta.x * wt1[4 * c + 0];
      att += ta.y * wt1[4 * c + 1];
      att += ta.z * wt1[4 * c + 2];
      att += ta.w * wt1[4 * c + 3];
    }
    float az = azx + azt + bz;
    float at = atx + att + bt;
    float zk = 1.0f / (1.0f + __expf(-az));
    float contrib = (1.0f - zk) * tanhf(at) * wl;
#pragma unroll
    for (int d = 1; d < 64; d <<= 1) contrib += __shfl_xor(contrib, d);
    if (lane == 0) out[node] = contrib + bl;
  }
}

extern "C" void kernel_launch(void* const* d_in, const int* in_sizes, int n_in,
                              void* d_out, int out_size, void* d_ws, size_t ws_size,
                              hipStream_t stream) {
  const float* x    = (const float*)d_in[0];
  const float* ew   = (const float*)d_in[1];
  const float* Wx0  = (const float*)d_in[2];
  const float* Wx1  = (const float*)d_in[3];
  const float* bx   = (const float*)d_in[4];
  const float* bh   = (const float*)d_in[7];
  const float* Wlin = (const float*)d_in[8];
  const float* blin = (const float*)d_in[9];
  const int*   ei   = (const int*)d_in[10];

  int N = in_sizes[0] / 32;
  int E = in_sizes[1];
  const int* row = ei;
  const int* col = ei + E;
  float* out = (float*)d_out;

  // pick largest KH=2^ks whose footprint fits ws_size (ks=0 matches round-4 size)
  int ks = 3;
  size_t headWords = 0;
  for (; ks >= 0; ks--) {
    size_t KH = (size_t)1 << ks;
    size_t nb2 = (KH * N + SB - 1) / SB;
    size_t wds = (size_t)N * 32 + N + KH * N + nb2 + 8;  // Tx + disq + offR + bsum + slack
    if (wds & 1) wds++;
    if (wds * 4 + (size_t)E * 8 <= ws_size) { headWords = wds; break; }
  }
  if (ks < 0) {  // shouldn't happen given round-4 ran; degrade to KH=1 anyway
    ks = 0;
    size_t KH = 1, nb2 = (KH * N + SB - 1) / SB;
    headWords = (size_t)N * 32 + N + KH * N + nb2 + 8;
    if (headWords & 1) headWords++;
  }
  int KH = 1 << ks;
  int khm = KH - 1;
  int n2 = KH * N;          // total sub-bins
  int nb = (n2 + SB - 1) / SB;

  // layout: [Tx N*32 (degR scratch lives here)][disq N][offR KH*N][bsum nb][pad][pairs E int2]
  float* Tx   = (float*)d_ws;
  float* degR = Tx;                         // KD*N floats, dead before gather writes Tx
  float* disq = Tx + (size_t)N * 32;
  int*   offR = (int*)(disq + N);
  int*   bsum = offR + n2;
  int2*  pairs = (int2*)((float*)d_ws + headWords);

  zero_kernel<<<256, THREADS, 0, stream>>>((int*)degR, (long)KD * N);
  zero_kernel<<<256, THREADS, 0, stream>>>(offR, (long)n2);
  int eb = (E + THREADS - 1) / THREADS;
  deg_hist_kernel<<<eb, THREADS, 0, stream>>>(ew, row, col, degR, offR, E, N, khm, ks);
  scan_blocks_kernel<<<nb, SB, 0, stream>>>(offR, bsum, n2);
  scan_top_kernel<<<1, SB, 0, stream>>>(bsum, nb);
  scan_add_disq_kernel<<<(n2 + THREADS - 1) / THREADS, THREADS, 0, stream>>>(offR, bsum, degR, disq, n2, N);
  bucket_kernel<<<eb, THREADS, 0, stream>>>(ew, row, col, disq, offR, pairs, E, khm, ks);
  long tthreads = (long)N * 64;
  gather_kernel<<<(int)((tthreads + THREADS - 1) / THREADS), THREADS, 0, stream>>>(x, offR, pairs, Tx, N, khm, ks);
  gate_kernel<<<512, THREADS, 0, stream>>>(x, Tx, Wx0, Wx1, bx, bh, Wlin, blin, out, N);
}

// Round 6
// 299.362 us; speedup vs baseline: 3.1838x; 1.0180x over previous
//
#include <hip/hip_runtime.h>

#define THREADS 256
#define SB 1024
// s_getreg imm: ID=20 (HW_REG_XCC_ID, gfx940+), offset=0, size=4 -> ((4-1)<<11)|20
#define XCC_GETREG_IMM 6164

__device__ __forceinline__ int xcd_id() {
  return (int)(__builtin_amdgcn_s_getreg(XCC_GETREG_IMM) & 7);
}

// ---------------- zero word regions ----------------
__global__ void zero_kernel(int* __restrict__ p, long n) {
  long i = (long)blockIdx.x * blockDim.x + threadIdx.x;
  long stride = (long)gridDim.x * blockDim.x;
  for (; i < n; i += stride) p[i] = 0;
}

// ---------------- degR[xcd][row] += w ; cntR[xcd][col]++ ----------------
template <bool SLICED>
__global__ void deg_hist_kernel(const float* __restrict__ w, const int* __restrict__ row,
                                const int* __restrict__ col, float* __restrict__ degR,
                                int* __restrict__ cntR, int E, int Np) {
  int x = SLICED ? xcd_id() : 0;
  int e = blockIdx.x * blockDim.x + threadIdx.x;
  if (e >= E) return;
  float* dp = &degR[(size_t)x * Np + row[e]];
  int*   cp = &cntR[(size_t)x * Np + col[e]];
  if (SLICED) {
    // XCD-local: executes in this XCD's L2, no device-coherent round trip
    __hip_atomic_fetch_add(dp, w[e], __ATOMIC_RELAXED, __HIP_MEMORY_SCOPE_WORKGROUP);
    __hip_atomic_fetch_add(cp, 1, __ATOMIC_RELAXED, __HIP_MEMORY_SCOPE_WORKGROUP);
  } else {
    atomicAdd(dp, w[e]);
    atomicAdd(cp, 1);
  }
}

// scan-order bin g (node-major, xcd-minor) -> storage address (xcd-major, padded)
template <bool SLICED>
__device__ __forceinline__ int bin_addr(int g, int Np) {
  return SLICED ? ((g & 7) * Np + (g >> 3)) : g;
}

// ---------------- device-wide exclusive scan, stage 1: per-block ----------------
template <bool SLICED>
__global__ void __launch_bounds__(SB)
scan_blocks_kernel(int* __restrict__ off, int* __restrict__ bsum, int n2, int Np) {
  __shared__ int s[SB];
  int t = threadIdx.x;
  int i = blockIdx.x * SB + t;
  int v = (i < n2) ? off[bin_addr<SLICED>(i, Np)] : 0;
  s[t] = v;
  __syncthreads();
  for (int d = 1; d < SB; d <<= 1) {
    int u = (t >= d) ? s[t - d] : 0;
    __syncthreads();
    s[t] += u;
    __syncthreads();
  }
  if (i < n2) off[bin_addr<SLICED>(i, Np)] = s[t] - v;   // exclusive within block
  if (t == SB - 1) bsum[blockIdx.x] = s[SB - 1];         // block total
}

// ---------------- stage 2: exclusive scan of block totals (nb <= 1024) ----------------
__global__ void __launch_bounds__(SB)
scan_top_kernel(int* __restrict__ bsum, int nb) {
  __shared__ int s[SB];
  int t = threadIdx.x;
  int v = (t < nb) ? bsum[t] : 0;
  s[t] = v;
  __syncthreads();
  for (int d = 1; d < SB; d <<= 1) {
    int u = (t >= d) ? s[t - d] : 0;
    __syncthreads();
    s[t] += u;
    __syncthreads();
  }
  if (t < nb) bsum[t] = s[t] - v;                        // exclusive
}

// ---------------- stage 3: add block offsets; reduce degR -> disq ----------------
template <bool SLICED>
__global__ void scan_add_disq_kernel(int* __restrict__ off, const int* __restrict__ bsum,
                                     const float* __restrict__ degR, float* __restrict__ disq,
                                     int n2, int N, int Np) {
  int i = blockIdx.x * blockDim.x + threadIdx.x;
  if (i < n2) off[bin_addr<SLICED>(i, Np)] += bsum[i >> 10];
  if (i < N) {
    float d = 0.f;
    if (SLICED) {
#pragma unroll
      for (int k = 0; k < 8; k++) d += degR[(size_t)k * Np + i];
    } else {
      d = degR[i];
    }
    disq[i] = (d > 0.0f) ? rsqrtf(d) : 0.0f;
  }
}

// ---------------- scatter edges into per-XCD sub-buckets ----------------
// After this kernel, offR[x*Np + c] = end of sub-bucket (c, x); sub-buckets of a
// node are contiguous in pairs, so node c spans [offR[7*Np+c-1], offR[7*Np+c]).
template <bool SLICED>
__global__ void bucket_kernel(const float* __restrict__ w, const int* __restrict__ row,
                              const int* __restrict__ col, const float* __restrict__ disq,
                              int* __restrict__ offR, int2* __restrict__ pairs,
                              int E, int Np) {
  int x = SLICED ? xcd_id() : 0;
  int e = blockIdx.x * blockDim.x + threadIdx.x;
  if (e >= E) return;
  int r = row[e];
  int c = col[e];
  float v = -w[e] * disq[r] * disq[c];
  int p;
  if (SLICED) {
    p = __hip_atomic_fetch_add(&offR[(size_t)x * Np + c], 1,
                               __ATOMIC_RELAXED, __HIP_MEMORY_SCOPE_WORKGROUP);
  } else {
    p = atomicAdd(&offR[c], 1);
  }
  pairs[p] = make_int2(r, __float_as_int(v));
}

// ---------------- gather: one wave per node, 8 edge-slots, no atomics ----------------
__global__ void gather_kernel(const float* __restrict__ x, const int* __restrict__ offEnd,
                              const int2* __restrict__ pairs, float* __restrict__ Tx, int n) {
  int wid = (int)(((long)blockIdx.x * blockDim.x + threadIdx.x) >> 6);
  if (wid >= n) return;
  int lane = threadIdx.x & 63;
  int slot = lane >> 3;     // 0..7  -> 8 edges in flight
  int f4 = lane & 7;        // float4 chunk of the 32-wide feature row
  int start = wid ? offEnd[wid - 1] : 0;
  int end = offEnd[wid];
  float4 acc = make_float4(0.f, 0.f, 0.f, 0.f);
  for (int i = start + slot; i < end; i += 8) {
    int2 pv = pairs[i];
    float v = __int_as_float(pv.y);
    float4 xr = *(const float4*)(x + (long)pv.x * 32 + f4 * 4);
    acc.x += v * xr.x;
    acc.y += v * xr.y;
    acc.z += v * xr.z;
    acc.w += v * xr.w;
  }
#pragma unroll
  for (int d = 8; d < 64; d <<= 1) {
    acc.x += __shfl_xor(acc.x, d);
    acc.y += __shfl_xor(acc.y, d);
    acc.z += __shfl_xor(acc.z, d);
    acc.w += __shfl_xor(acc.w, d);
  }
  if (slot == 0) *(float4*)(Tx + (long)wid * 32 + f4 * 4) = acc;
}

// ---------------- fused gates + output: one wave per node, lane = output k ----------------
__global__ void __launch_bounds__(THREADS, 2)
gate_kernel(const float* __restrict__ x, const float* __restrict__ Tx,
            const float* __restrict__ Wx0, const float* __restrict__ Wx1,
            const float* __restrict__ bx, const float* __restrict__ bh,
            const float* __restrict__ Wlin, const float* __restrict__ blin,
            float* __restrict__ out, int n) {
  int lane = threadIdx.x & 63;
  int wave = blockIdx.x * (THREADS / 64) + (threadIdx.x >> 6);
  int nwaves = gridDim.x * (THREADS / 64);

  float wz0[32], wz1[32], wt0[32], wt1[32];
#pragma unroll
  for (int f = 0; f < 32; f++) {
    wz0[f] = Wx0[f * 64 + lane];
    wz1[f] = Wx1[f * 64 + lane];
    wt0[f] = Wx0[4096 + f * 64 + lane];
    wt1[f] = Wx1[4096 + f * 64 + lane];
  }
  float bz = bx[lane] + bh[lane];
  float bt = bx[128 + lane] + bh[128 + lane];
  float wl = Wlin[lane];
  float bl = blin[0];

  for (int node = wave; node < n; node += nwaves) {
    const float4* xp = (const float4*)(x + (long)node * 32);
    const float4* tp = (const float4*)(Tx + (long)node * 32);
    float azx = 0.f, azt = 0.f, atx = 0.f, att = 0.f;
#pragma unroll
    for (int c = 0; c < 8; c++) {
      float4 xa = xp[c];
      float4 ta = tp[c];
      azx += xa.x * wz0[4 * c + 0];
      azx += xa.y * wz0[4 * c + 1];
      azx += xa.z * wz0[4 * c + 2];
      azx += xa.w * wz0[4 * c + 3];
      azt += ta.x * wz1[4 * c + 0];
      azt += ta.y * wz1[4 * c + 1];
      azt += ta.z * wz1[4 * c + 2];
      azt += ta.w * wz1[4 * c + 3];
      atx += xa.x * wt0[4 * c + 0];
      atx += xa.y * wt0[4 * c + 1];
      atx += xa.z * wt0[4 * c + 2];
      atx += xa.w * wt0[4 * c + 3];
      att += ta.x * wt1[4 * c + 0];
      att += ta.y * wt1[4 * c + 1];
      att += ta.z * wt1[4 * c + 2];
      att += ta.w * wt1[4 * c + 3];
    }
    float az = azx + azt + bz;
    float at = atx + att + bt;
    float zk = 1.0f / (1.0f + __expf(-az));
    float contrib = (1.0f - zk) * tanhf(at) * wl;
#pragma unroll
    for (int d = 1; d < 64; d <<= 1) contrib += __shfl_xor(contrib, d);
    if (lane == 0) out[node] = contrib + bl;
  }
}

extern "C" void kernel_launch(void* const* d_in, const int* in_sizes, int n_in,
                              void* d_out, int out_size, void* d_ws, size_t ws_size,
                              hipStream_t stream) {
  const float* x    = (const float*)d_in[0];
  const float* ew   = (const float*)d_in[1];
  const float* Wx0  = (const float*)d_in[2];
  const float* Wx1  = (const float*)d_in[3];
  const float* bx   = (const float*)d_in[4];
  const float* bh   = (const float*)d_in[7];
  const float* Wlin = (const float*)d_in[8];
  const float* blin = (const float*)d_in[9];
  const int*   ei   = (const int*)d_in[10];

  int N = in_sizes[0] / 32;
  int E = in_sizes[1];
  const int* row = ei;
  const int* col = ei + E;
  float* out = (float*)d_out;

  int Np = (N + 63) & ~63;          // 256B-aligned slice stride (no shared lines)
  int eb = (E + THREADS - 1) / THREADS;
  long tthreads = (long)N * 64;

  // sliced layout: [Tx 32N f32 (degR 8*Np + bsum alias here)][disq N][offR 8*Np][pad][pairs E int2]
  size_t slicedHead = (size_t)N * 32 + N + (size_t)8 * Np + 8;
  if (slicedHead & 1) slicedHead++;
  size_t slicedNeed = slicedHead * 4 + (size_t)E * 8;

  if (slicedNeed <= ws_size) {
    float* Tx   = (float*)d_ws;
    float* degR = Tx;                               // 8*Np f32, dead before gather
    int*   bsum = (int*)(Tx + (size_t)8 * Np);      // in Tx region, dead before gather
    float* disq = Tx + (size_t)N * 32;
    int*   offR = (int*)(disq + N);                 // 8*Np ints (cnt -> scanned base -> pos)
    int2*  pairs = (int2*)((float*)d_ws + slicedHead);
    int n2 = 8 * N;
    int nb = (n2 + SB - 1) / SB;

    zero_kernel<<<256, THREADS, 0, stream>>>((int*)degR, (long)8 * Np);
    zero_kernel<<<256, THREADS, 0, stream>>>(offR, (long)8 * Np);
    deg_hist_kernel<true><<<eb, THREADS, 0, stream>>>(ew, row, col, degR, offR, E, Np);
    scan_blocks_kernel<true><<<nb, SB, 0, stream>>>(offR, bsum, n2, Np);
    scan_top_kernel<<<1, SB, 0, stream>>>(bsum, nb);
    scan_add_disq_kernel<true><<<(n2 + THREADS - 1) / THREADS, THREADS, 0, stream>>>(
        offR, bsum, degR, disq, n2, N, Np);
    bucket_kernel<true><<<eb, THREADS, 0, stream>>>(ew, row, col, disq, offR, pairs, E, Np);
    gather_kernel<<<(int)((tthreads + THREADS - 1) / THREADS), THREADS, 0, stream>>>(
        x, offR + (size_t)7 * Np, pairs, Tx, N);
    gate_kernel<<<512, THREADS, 0, stream>>>(x, Tx, Wx0, Wx1, bx, bh, Wlin, blin, out, N);
  } else {
    // fallback: device-scope atomics, single copy (round-4 behavior)
    float* Tx   = (float*)d_ws;
    float* degR = Tx;                               // N f32
    int*   bsum = (int*)(Tx + N);
    float* disq = Tx + (size_t)N * 32;
    int*   offR = (int*)(disq + N);                 // N ints
    size_t head = (size_t)N * 32 + N + N + 8;
    if (head & 1) head++;
    int2* pairs = (int2*)((float*)d_ws + head);
    int n2 = N;
    int nb = (n2 + SB - 1) / SB;

    zero_kernel<<<256, THREADS, 0, stream>>>((int*)degR, (long)N);
    zero_kernel<<<256, THREADS, 0, stream>>>(offR, (long)N);
    deg_hist_kernel<false><<<eb, THREADS, 0, stream>>>(ew, row, col, degR, offR, E, Np);
    scan_blocks_kernel<false><<<nb, SB, 0, stream>>>(offR, bsum, n2, Np);
    scan_top_kernel<<<1, SB, 0, stream>>>(bsum, nb);
    scan_add_disq_kernel<false><<<(n2 + THREADS - 1) / THREADS, THREADS, 0, stream>>>(
        offR, bsum, degR, disq, n2, N, Np);
    bucket_kernel<false><<<eb, THREADS, 0, stream>>>(ew, row, col, disq, offR, pairs, E, Np);
    gather_kernel<<<(int)((tthreads + THREADS - 1) / THREADS), THREADS, 0, stream>>>(
        x, offR, pairs, Tx, N);
    gate_kernel<<<512, THREADS, 0, stream>>>(x, Tx, Wx0, Wx1, bx, bh, Wlin, blin, out, N);
  }
}